// Round 5
// baseline (1215.287 us; speedup 1.0000x reference)
//
#include <hip/hip_runtime.h>
#include <hip/hip_bf16.h>
#include <math.h>

// ---------------------------------------------------------------------------
// BNAF flow (DIM=64, HID=32, B=1024).  R20: ONE persistent mega-kernel.
// All 12 compute stages (prep, 3x{gemm0, gemm1, act_grad, tail}) run inside
// a single 512-block dispatch separated by 12 device-scope grid barriers
// (two-level atomic tree, agent scope). Stage bodies = R19 (bit-identical
// math). Co-residency guaranteed: launch_bounds(256,2), LDS 34.3KB -> 2
// blocks/CU. 1 memset + 1 kernel dispatch total.
// ---------------------------------------------------------------------------

#define DIMN 64
#define BATCH 1024
#define HIDF 2048   // DIM*HID
#define SPLITK 4
#define NT2 32      // out2 partial count (= HIDF/64 n-tiles)
#define NB 512      // persistent blocks (2 per CU)
#define NGRP 16     // barrier groups (32 blocks each)

typedef __attribute__((ext_vector_type(8))) short short8;
typedef __attribute__((ext_vector_type(4))) float floatx4;
typedef __hip_bfloat16 bf16;

__device__ __forceinline__ float softplusf_(float t) {
    return fmaxf(t, 0.f) + log1pf(__expf(-fabsf(t)));
}

__device__ __forceinline__ float bf2f(short v) {
    union { unsigned u; float f; } x;
    x.u = ((unsigned)(unsigned short)v) << 16;
    return x.f;
}

__device__ __forceinline__ void gl_lds16(const void* g, void* l) {
    __builtin_amdgcn_global_load_lds(
        (const __attribute__((address_space(1))) unsigned int*)g,
        (__attribute__((address_space(3))) unsigned int*)l, 16, 0, 0);
}

__device__ __forceinline__ void tanh_sech2_(float p, float& th, float& s2) {
    float t = __expf(-2.f * fabsf(p));
    float opt = 1.f + t;
    float inv = 1.f / opt;
    th = copysignf((1.f - t) * inv, p);
    s2 = 4.f * t * inv * inv;
}

// ---------------------------------------------------------------------------
// Grid barrier: two-level (16 groups x 32 blocks), agent-scope atomics,
// counters padded to 128B lines. Requires all NB blocks co-resident.
// bar layout (ints, stride 32): [g*32] group counters, [16*32] root,
// [17*32] generation.
// ---------------------------------------------------------------------------
__device__ __forceinline__ void gridbar(int* bar, int bid)
{
    __syncthreads();
    if (threadIdx.x == 0) {
        int* gcnt = bar + (bid & (NGRP - 1)) * 32;
        int* root = bar + NGRP * 32;
        int* gen  = bar + (NGRP + 1) * 32;
        int g = __hip_atomic_load(gen, __ATOMIC_RELAXED, __HIP_MEMORY_SCOPE_AGENT);
        int a = __hip_atomic_fetch_add(gcnt, 1, __ATOMIC_ACQ_REL, __HIP_MEMORY_SCOPE_AGENT) + 1;
        if (a == NB / NGRP) {
            __hip_atomic_store(gcnt, 0, __ATOMIC_RELAXED, __HIP_MEMORY_SCOPE_AGENT);
            int r = __hip_atomic_fetch_add(root, 1, __ATOMIC_ACQ_REL, __HIP_MEMORY_SCOPE_AGENT) + 1;
            if (r == NGRP) {
                __hip_atomic_store(root, 0, __ATOMIC_RELAXED, __HIP_MEMORY_SCOPE_AGENT);
                __hip_atomic_fetch_add(gen, 1, __ATOMIC_RELEASE, __HIP_MEMORY_SCOPE_AGENT);
            } else {
                while (__hip_atomic_load(gen, __ATOMIC_ACQUIRE, __HIP_MEMORY_SCOPE_AGENT) == g)
                    __builtin_amdgcn_s_sleep(2);
            }
        } else {
            while (__hip_atomic_load(gen, __ATOMIC_ACQUIRE, __HIP_MEMORY_SCOPE_AGENT) == g)
                __builtin_amdgcn_s_sleep(2);
        }
    }
    __syncthreads();
}

// ---------------------------------------------------------------------------
// prep row worker (R16 form): one wave per output row r of W (out_f x INF).
// ---------------------------------------------------------------------------
template<int INF>
__device__ __forceinline__ void prep_row(
    const float* __restrict__ W, const float* __restrict__ dw,
    void* __restrict__ wn_out, float* __restrict__ eg,
    int r, int lane, int out_f, int ob, int ib, int transpose, int bf16out)
{
    constexpr int NI = INF / 64;
    int d = r / ob;
    int c0 = d * ib;
    int c1 = c0 + ib;
    const float* Wr = W + (size_t)r * INF;

    float vv[NI];
    float ss = 0.f;
#pragma unroll
    for (int i = 0; i < NI; ++i) {
        int c = lane + i * 64;
        float wraw = Wr[c];
        float wv = (c < c0) ? wraw : ((c < c1) ? __expf(wraw) : 0.f);
        vv[i] = wv;
        ss += wv * wv;
    }
    for (int off = 32; off > 0; off >>= 1) ss += __shfl_xor(ss, off, 64);

    float dwr = dw[r];
    float scale = __expf(dwr) / sqrtf(ss);
    float logt = dwr - 0.5f * __logf(ss);

#pragma unroll
    for (int i = 0; i < NI; ++i) {
        int c = lane + i * 64;
        float val = scale * vv[i];
        if (bf16out) {
            ((bf16*)wn_out)[(size_t)r * INF + c] = __float2bfloat16(val);
        } else if (transpose) {
            ((float*)wn_out)[(size_t)c * out_f + r] = val;
        } else {
            ((float*)wn_out)[(size_t)r * INF + c] = val;
        }
    }
    if (lane < ib) eg[(size_t)r * ib + lane] = __expf(logt + Wr[c0 + lane]);
}

// ---------------------------------------------------------------------------
// gemm0 stage body (R16/R19 form). task = (bx in [0,8), by in [0,64)).
// ---------------------------------------------------------------------------
__device__ void dev_gemm0(int bx, int by,
    const float* __restrict__ xin, const float* __restrict__ wn0T,
    const float* __restrict__ bias, const float* __restrict__ eg0,
    bf16* __restrict__ h0, bf16* __restrict__ g0e, char* smem_, int tid)
{
    float (*xs)[DIMN] = (float(*)[DIMN])smem_;
    int b0 = by * 16;
    {
        const float4* src = (const float4*)(xin + (size_t)b0 * DIMN);
        ((float4*)xs)[tid] = src[tid];
    }
    __syncthreads();
    int n = bx * 256 + tid;

    float acc[16];
#pragma unroll
    for (int j = 0; j < 16; ++j) acc[j] = 0.f;

#pragma unroll 4
    for (int c4 = 0; c4 < 16; ++c4) {
        int c = c4 * 4;
        float w0 = wn0T[(size_t)(c + 0) * HIDF + n];
        float w1 = wn0T[(size_t)(c + 1) * HIDF + n];
        float w2 = wn0T[(size_t)(c + 2) * HIDF + n];
        float w3 = wn0T[(size_t)(c + 3) * HIDF + n];
#pragma unroll
        for (int j = 0; j < 16; ++j) {
            float4 x4 = *(const float4*)&xs[j][c];
            acc[j] = fmaf(x4.x, w0, acc[j]);
            acc[j] = fmaf(x4.y, w1, acc[j]);
            acc[j] = fmaf(x4.z, w2, acc[j]);
            acc[j] = fmaf(x4.w, w3, acc[j]);
        }
    }
    float bv = bias[n], egv = eg0[n];
#pragma unroll
    for (int j = 0; j < 16; ++j) {
        float p = acc[j] + bv;
        float th, s2;
        tanh_sech2_(p, th, s2);
        size_t idx = (size_t)(b0 + j) * HIDF + n;
        h0[idx] = __float2bfloat16(th);
        g0e[idx] = __float2bfloat16(egv * s2);
    }
    __syncthreads();
}

// ---------------------------------------------------------------------------
// gemm1 stage body: live triangular (jn,kz) pairs only. 40 pairs x 8 m-tiles.
// ---------------------------------------------------------------------------
__constant__ unsigned char G1_JN[40] = {
    3,4,5,6,7,7,8,8,9,9,10,10,11,11,11,12,12,12,13,13,13,14,14,14,
    15,15,15,15, 2,6,10,14, 1,5,9,13, 0,4,8,12 };
__constant__ unsigned char G1_KZ[40] = {
    0,0,0,0,0,1,0,1,0,1, 0, 1, 0, 1, 2, 0, 1, 2, 0, 1, 2, 0, 1, 2,
     0, 1, 2, 3, 0,1, 2, 3, 0,1,2,3, 0,1,2,3 };

#define G1BK 64
__device__ void dev_gemm1(int pr, int my,
    const bf16* __restrict__ A, const bf16* __restrict__ B,
    bf16* __restrict__ part, char* smem_, int tid)
{
    const int K = HIDF, N = HIDF;
    int jn = G1_JN[pr];
    int kz = G1_KZ[pr];
    int kbase = kz * (K / SPLITK);
    int kend = (jn + 1) * 128 - kbase;
    if (kend > K / SPLITK) kend = K / SPLITK;

    short* As = (short*)smem_;            // [128][64] swizzled, 16 KB
    short* Bs = (short*)(smem_ + 16384);  // [128][64] swizzled, 16 KB
    int lane = tid & 63;
    int wave = tid >> 6;
    int n0 = jn * 128;
    int m0 = my * 128;
    int wr = wave >> 1;
    int wc = wave & 1;

    int rf = lane & 15;
    int q = lane >> 4;

    const char* agp[4];
    const char* bgp[4];
    char* alds[4];
    char* blds[4];
#pragma unroll
    for (int s = 0; s < 4; ++s) {
        int c = tid + s * 256;
        int row = c >> 3;
        int kc = (c & 7) ^ (row & 7);
        agp[s] = (const char*)A + ((size_t)(m0 + row) * K + kbase) * 2 + kc * 16;
        bgp[s] = (const char*)B + ((size_t)(n0 + row) * K + kbase) * 2 + kc * 16;
        alds[s] = (char*)As + c * 16;
        blds[s] = (char*)Bs + c * 16;
    }

    floatx4 acc[4][4];
#pragma unroll
    for (int i = 0; i < 4; ++i)
#pragma unroll
        for (int j = 0; j < 4; ++j) acc[i][j] = (floatx4){0.f, 0.f, 0.f, 0.f};

    int rowA0 = wr * 64 + rf;
    int rowB0 = wc * 64 + rf;

    for (int k0 = 0; k0 < kend; k0 += G1BK) {
        size_t kb = (size_t)k0 * 2;
        __syncthreads();
#pragma unroll
        for (int s = 0; s < 4; ++s) {
            gl_lds16(agp[s] + kb, alds[s]);
            gl_lds16(bgp[s] + kb, blds[s]);
        }
        __syncthreads();

#pragma unroll
        for (int s = 0; s < 2; ++s) {
            short8 af[4], bfv[4];
#pragma unroll
            for (int i = 0; i < 4; ++i) {
                int row = rowA0 + i * 16;
                af[i] = *(const short8*)&As[row * 64 + (((s * 4 + q) ^ (row & 7)) * 8)];
            }
#pragma unroll
            for (int j = 0; j < 4; ++j) {
                int row = rowB0 + j * 16;
                bfv[j] = *(const short8*)&Bs[row * 64 + (((s * 4 + q) ^ (row & 7)) * 8)];
            }
#pragma unroll
            for (int i = 0; i < 4; ++i)
#pragma unroll
                for (int j = 0; j < 4; ++j)
                    acc[i][j] = __builtin_amdgcn_mfma_f32_16x16x32_bf16(af[i], bfv[j], acc[i][j], 0, 0, 0);
        }
    }

    bf16* pk = part + (size_t)kz * BATCH * HIDF;
    int col = lane & 15;
    int rq = (lane >> 4) * 4;
#pragma unroll
    for (int i = 0; i < 4; ++i) {
#pragma unroll
        for (int j = 0; j < 4; ++j) {
            int n = n0 + wc * 64 + j * 16 + col;
#pragma unroll
            for (int r = 0; r < 4; ++r) {
                int m = m0 + wr * 64 + i * 16 + rq + r;
                pk[(size_t)m * N + n] = __float2bfloat16(acc[i][j][r]);
            }
        }
    }
    __syncthreads();
}

// ---------------------------------------------------------------------------
// act_grad stage body (R19 branch-free form). task = (bx in [0,32), by in [0,16)).
// ---------------------------------------------------------------------------
__device__ void dev_actgrad(int bx, int by,
    const bf16* __restrict__ part, const float* __restrict__ bias,
    const float* __restrict__ e1, const bf16* __restrict__ g0e,
    const bf16* __restrict__ wn2b,
    bf16* __restrict__ grad1e, float* __restrict__ out2p, char* smem_, int tid)
{
    float* g0s = (float*)smem_;                       // 64 x 68 floats
    short* h1s = (short*)(smem_ + 17408);             // 64 x 68 shorts
    short* Bs2 = (short*)(smem_ + 17408 + 8704);      // 64 x 64 swizzled

    int lane = tid & 63;
    int wave = tid >> 6;
    int n0 = bx * 64;
    int b0 = by * 64;
    int np = (bx >> 3) + 1;

    {
        int c0c = tid, c1c = tid + 256;
        int r0 = c0c >> 3, k0c = (c0c & 7) ^ (r0 & 7);
        int r1 = c1c >> 3, k1c = (c1c & 7) ^ (r1 & 7);
        gl_lds16((const char*)wn2b + ((size_t)r0 * HIDF + n0) * 2 + k0c * 16,
                 (char*)Bs2 + c0c * 16);
        gl_lds16((const char*)wn2b + ((size_t)r1 * HIDF + n0) * 2 + k1c * 16,
                 (char*)Bs2 + c1c * 16);
    }

    for (int s = tid; s < 512; s += 256) {
        int row = s >> 3, c8 = s & 7;
        short8 v = *(const short8*)((const short*)g0e +
                                    (size_t)(b0 + row) * HIDF + n0 + c8 * 8);
        float4 lo = { bf2f(v[0]), bf2f(v[1]), bf2f(v[2]), bf2f(v[3]) };
        float4 hi = { bf2f(v[4]), bf2f(v[5]), bf2f(v[6]), bf2f(v[7]) };
        *(float4*)&g0s[row * 68 + c8 * 8] = lo;
        *(float4*)&g0s[row * 68 + c8 * 8 + 4] = hi;
    }

    int g = tid >> 6;
    int nl = tid & 63;
    int n = n0 + nl;

    float4 er[8];
    const float4* e1r = (const float4*)(e1 + (size_t)n * 32);
#pragma unroll
    for (int qq = 0; qq < 8; ++qq) er[qq] = e1r[qq];

    float bv = bias[n];
    int kb2 = nl & 32;
    const bf16* pp0 = part;
    const bf16* pp1 = (np > 1) ? part + (size_t)1 * BATCH * HIDF : part;
    const bf16* pp2 = (np > 2) ? part + (size_t)2 * BATCH * HIDF : part;
    const bf16* pp3 = (np > 3) ? part + (size_t)3 * BATCH * HIDF : part;
    float m1 = (np > 1) ? 1.f : 0.f;
    float m2 = (np > 2) ? 1.f : 0.f;
    float m3 = (np > 3) ? 1.f : 0.f;

    __syncthreads();

#pragma unroll
    for (int t = 0; t < 16; ++t) {
        int bl = g * 16 + t;
        int b = b0 + bl;
        size_t idx = (size_t)b * HIDF + n;
        float l0 = __bfloat162float(pp0[idx]);
        float l1 = __bfloat162float(pp1[idx]);
        float l2 = __bfloat162float(pp2[idx]);
        float l3 = __bfloat162float(pp3[idx]);
        float pre = bv + l0;
        pre = fmaf(m1, l1, pre);
        pre = fmaf(m2, l2, pre);
        pre = fmaf(m3, l3, pre);
        float th, s2;
        tanh_sech2_(pre, th, s2);
        const float* g0row = &g0s[bl * 68 + kb2];
        float dot = 0.f;
#pragma unroll
        for (int qq = 0; qq < 8; ++qq) {
            float4 gv = *(const float4*)&g0row[qq * 4];
            dot = fmaf(gv.x, er[qq].x, dot);
            dot = fmaf(gv.y, er[qq].y, dot);
            dot = fmaf(gv.z, er[qq].z, dot);
            dot = fmaf(gv.w, er[qq].w, dot);
        }
        bf16 thb = __float2bfloat16(th);
        h1s[bl * 68 + nl] = *(const short*)&thb;
        grad1e[idx] = __float2bfloat16(dot * s2);
    }
    __syncthreads();

    int rf = lane & 15;
    int q = lane >> 4;
    floatx4 acc2[4];
#pragma unroll
    for (int j = 0; j < 4; ++j) acc2[j] = (floatx4){0.f, 0.f, 0.f, 0.f};

#pragma unroll
    for (int s = 0; s < 2; ++s) {
        int rowa = wave * 16 + rf;
        short8 af = *(const short8*)&h1s[rowa * 68 + s * 32 + q * 8];
#pragma unroll
        for (int j = 0; j < 4; ++j) {
            int rowb = j * 16 + rf;
            int cp = (s * 4 + q) ^ (rowb & 7);
            short8 bfv = *(const short8*)&Bs2[rowb * 64 + cp * 8];
            acc2[j] = __builtin_amdgcn_mfma_f32_16x16x32_bf16(af, bfv, acc2[j], 0, 0, 0);
        }
    }

    float* outk = out2p + (size_t)bx * BATCH * DIMN;
    int col = lane & 15;
    int rq = (lane >> 4) * 4;
#pragma unroll
    for (int j = 0; j < 4; ++j) {
#pragma unroll
        for (int r = 0; r < 4; ++r) {
            int m = b0 + wave * 16 + rq + r;
            outk[(size_t)m * DIMN + j * 16 + col] = acc2[j][r];
        }
    }
    __syncthreads();
}

// ---------------------------------------------------------------------------
// tail stage bodies. task t in [0,256): 4 batch rows per block.
// ---------------------------------------------------------------------------
__device__ void dev_tail_trans(int t,
    const float* __restrict__ out2p, const float* __restrict__ b2,
    const float* __restrict__ e2, const bf16* __restrict__ grad1e,
    const float* __restrict__ x_cur, const float* __restrict__ gate,
    float* __restrict__ x_next, float* __restrict__ ldj, int accum_ldj, int tid)
{
    int b = t * 4 + (tid >> 6);
    int n = tid & 63;

    float o = b2[n];
#pragma unroll
    for (int p = 0; p < NT2; ++p)
        o += out2p[(size_t)p * BATCH * DIMN + (size_t)b * DIMN + n];

    float gt = gate[0];
    float sg = 1.f / (1.f + __expf(-gt));
    float xo = sg * o + (1.f - sg) * x_cur[(size_t)b * DIMN + n];
    x_next[(size_t)b * DIMN + (63 - n)] = xo;

    const short8* gr = (const short8*)((const short*)grad1e + (size_t)b * HIDF + n * 32);
    const float4* gc = (const float4*)(e2 + n * 32);
    float s = 0.f;
#pragma unroll
    for (int q = 0; q < 4; ++q) {
        short8 a8 = gr[q];
        float4 c0 = gc[2 * q], c1 = gc[2 * q + 1];
        s = fmaf(bf2f(a8[0]), c0.x, s);
        s = fmaf(bf2f(a8[1]), c0.y, s);
        s = fmaf(bf2f(a8[2]), c0.z, s);
        s = fmaf(bf2f(a8[3]), c0.w, s);
        s = fmaf(bf2f(a8[4]), c1.x, s);
        s = fmaf(bf2f(a8[5]), c1.y, s);
        s = fmaf(bf2f(a8[6]), c1.z, s);
        s = fmaf(bf2f(a8[7]), c1.w, s);
    }
    float gF = __logf(fmaxf(s, 1e-45f));
    float contrib = softplusf_(gF + gt) - softplusf_(gt);
    for (int off = 32; off > 0; off >>= 1) contrib += __shfl_xor(contrib, off, 64);
    if (n == 0) ldj[b] = accum_ldj ? (ldj[b] + contrib) : contrib;
}

__device__ void dev_tail_final(int t,
    const float* __restrict__ out2p, const float* __restrict__ b2,
    const float* __restrict__ e2, const bf16* __restrict__ grad1e,
    const float* __restrict__ ldj, float* __restrict__ out, int tid)
{
    int b = t * 4 + (tid >> 6);
    int n = tid & 63;

    float o = b2[n];
#pragma unroll
    for (int p = 0; p < NT2; ++p)
        o += out2p[(size_t)p * BATCH * DIMN + (size_t)b * DIMN + n];

    const short8* gr = (const short8*)((const short*)grad1e + (size_t)b * HIDF + n * 32);
    const float4* gc = (const float4*)(e2 + n * 32);
    float s = 0.f;
#pragma unroll
    for (int q = 0; q < 4; ++q) {
        short8 a8 = gr[q];
        float4 c0 = gc[2 * q], c1 = gc[2 * q + 1];
        s = fmaf(bf2f(a8[0]), c0.x, s);
        s = fmaf(bf2f(a8[1]), c0.y, s);
        s = fmaf(bf2f(a8[2]), c0.z, s);
        s = fmaf(bf2f(a8[3]), c0.w, s);
        s = fmaf(bf2f(a8[4]), c1.x, s);
        s = fmaf(bf2f(a8[5]), c1.y, s);
        s = fmaf(bf2f(a8[6]), c1.z, s);
        s = fmaf(bf2f(a8[7]), c1.w, s);
    }
    float gF = __logf(fmaxf(s, 1e-45f));

    float contrib = gF - 0.5f * o * o - 0.91893853320467274f;
    for (int off = 32; off > 0; off >>= 1) contrib += __shfl_xor(contrib, off, 64);
    if (n == 0) out[b] = ldj[b] + contrib;
}

// ---------------------------------------------------------------------------
// The mega-kernel.
// ---------------------------------------------------------------------------
struct MegaArgs {
    const float* x;
    const float* gate0;
    const float* gate1;
    const float* Wp[27];
    float* wn0T; float* eg0;
    bf16* wn1; float* e1;
    bf16* wn2b; float* e2;
    bf16* h0; bf16* part; bf16* g0e; bf16* grad1e;
    float* out2p; float* x1; float* x2; float* ldj;
    float* outp;
    int* bar;
};

__global__ __launch_bounds__(256, 2) void mega(MegaArgs A)
{
    __shared__ __align__(16) char smem[34304];
    const int bid = blockIdx.x;
    const int tid = threadIdx.x;
    const int wave = tid >> 6, lane = tid & 63;

    // ---- stage 0: prep (all 3 flows) : 3120 block-tasks x 4 waves ----
    for (int tb = bid; tb < 3120; tb += NB) {
        int blk = tb * 4 + wave;
        int f = blk / 4160;
        int rem = blk - f * 4160;
        float* wn0T = A.wn0T + (size_t)f * DIMN * HIDF;
        float* eg0  = A.eg0  + (size_t)f * HIDF;
        bf16* wn1   = A.wn1  + (size_t)f * HIDF * HIDF;
        float* e1   = A.e1   + (size_t)f * HIDF * 32;
        bf16* wn2b  = A.wn2b + (size_t)f * DIMN * HIDF;
        float* e2   = A.e2   + (size_t)f * DIMN * 32;
        if (rem < HIDF) {
            prep_row<DIMN>(A.Wp[f*9+0], A.Wp[f*9+1], wn0T, eg0, rem, lane, HIDF, 32, 1, 1, 0);
        } else if (rem < 2 * HIDF) {
            prep_row<HIDF>(A.Wp[f*9+3], A.Wp[f*9+4], wn1, e1, rem - HIDF, lane, HIDF, 32, 32, 0, 1);
        } else {
            prep_row<HIDF>(A.Wp[f*9+6], A.Wp[f*9+7], wn2b, e2, rem - 2*HIDF, lane, DIMN, 1, 32, 0, 1);
        }
    }
    gridbar(A.bar, bid);

    // ---- gemm0 flow 0 ----
    if (bid < 512)
        dev_gemm0(bid & 7, bid >> 3, A.x, A.wn0T, A.Wp[2], A.eg0, A.h0, A.g0e, smem, tid);
    gridbar(A.bar, bid);

    const float* xcur = A.x;
#pragma unroll 1
    for (int f = 0; f < 3; ++f) {
        const bf16* wn1f  = A.wn1  + (size_t)f * HIDF * HIDF;
        const float* e1f  = A.e1   + (size_t)f * HIDF * 32;
        const bf16* wn2bf = A.wn2b + (size_t)f * DIMN * HIDF;
        const float* e2f  = A.e2   + (size_t)f * DIMN * 32;

        // gemm1: 320 tasks
        if (bid < 320)
            dev_gemm1(bid >> 3, bid & 7, A.h0, wn1f, A.part, smem, tid);
        gridbar(A.bar, bid);

        // act_grad: 512 tasks
        dev_actgrad(bid & 31, bid >> 5, A.part, A.Wp[f*9+5], e1f, A.g0e,
                    wn2bf, A.grad1e, A.out2p, smem, tid);
        gridbar(A.bar, bid);

        if (f < 2) {
            const float* gate = (f == 0) ? A.gate0 : A.gate1;
            float* xnext = (f == 0) ? A.x1 : A.x2;
            if (bid < 256)
                dev_tail_trans(bid, A.out2p, A.Wp[f*9+8], e2f, A.grad1e,
                               xcur, gate, xnext, A.ldj, f, tid);
            gridbar(A.bar, bid);

            dev_gemm0(bid & 7, bid >> 3, xnext,
                      A.wn0T + (size_t)(f+1) * DIMN * HIDF, A.Wp[(f+1)*9+2],
                      A.eg0 + (size_t)(f+1) * HIDF, A.h0, A.g0e, smem, tid);
            gridbar(A.bar, bid);
            xcur = xnext;
        } else {
            if (bid < 256)
                dev_tail_final(bid, A.out2p, A.Wp[f*9+8], e2f, A.grad1e,
                               A.ldj, A.outp, tid);
        }
    }
}

// ---------------------------------------------------------------------------
extern "C" void kernel_launch(void* const* d_in, const int* in_sizes, int n_in,
                              void* d_out, int out_size, void* d_ws, size_t ws_size,
                              hipStream_t stream)
{
    (void)in_sizes; (void)n_in; (void)out_size; (void)ws_size;

    char* ws = (char*)d_ws;
    size_t ofs = 0;
    auto alloc = [&](size_t bytes) { char* p = ws + ofs; ofs += (bytes + 255) & ~(size_t)255; return p; };

    MegaArgs A;
    A.x = (const float*)d_in[0];
    A.gate0 = (const float*)d_in[28];
    A.gate1 = (const float*)d_in[29];
    for (int f = 0; f < 3; ++f)
        for (int i = 0; i < 9; ++i)
            A.Wp[f * 9 + i] = (const float*)d_in[1 + f * 9 + i];

    A.wn1    = (bf16*)alloc((size_t)3 * HIDF * HIDF * 2);   // 24 MB
    A.wn2b   = (bf16*)alloc((size_t)3 * DIMN * HIDF * 2);
    A.wn0T   = (float*)alloc((size_t)3 * DIMN * HIDF * 4);
    A.eg0    = (float*)alloc((size_t)3 * HIDF * 4);
    A.e1     = (float*)alloc((size_t)3 * HIDF * 32 * 4);
    A.e2     = (float*)alloc((size_t)3 * DIMN * 32 * 4);
    A.h0     = (bf16*)alloc((size_t)BATCH * HIDF * 2);
    A.part   = (bf16*)alloc((size_t)SPLITK * BATCH * HIDF * 2); // 16 MB
    A.g0e    = (bf16*)alloc((size_t)BATCH * HIDF * 2);
    A.grad1e = (bf16*)alloc((size_t)BATCH * HIDF * 2);
    A.out2p  = (float*)alloc((size_t)NT2 * BATCH * DIMN * 4);   // 8 MB
    A.x1     = (float*)alloc((size_t)BATCH * DIMN * 4);
    A.x2     = (float*)alloc((size_t)BATCH * DIMN * 4);
    A.ldj    = (float*)alloc(BATCH * 4);
    A.bar    = (int*)alloc((NGRP + 2) * 32 * sizeof(int));
    A.outp   = (float*)d_out;

    hipMemsetAsync(A.bar, 0, (NGRP + 2) * 32 * sizeof(int), stream);
    mega<<<dim3(NB), dim3(256), 0, stream>>>(A);
}

// Round 6
// 664.051 us; speedup vs baseline: 1.8301x; 1.8301x over previous
//
#include <hip/hip_runtime.h>
#include <hip/hip_bf16.h>
#include <math.h>

// ---------------------------------------------------------------------------
// BNAF flow (DIM=64, HID=32, B=1024).  R21: R20 persistent mega-kernel with
// the grid barrier fixed. R20's single-line generation flag melted under 512
// agent-scope ACQUIRE spinners (~75us/barrier, +140MB poll fetch). Now:
// two-level arrival (16 groups x 32) + root fans out to 16 PER-GROUP flag
// lines; pollers spin RELAXED+s_sleep on their group's line (32/line), one
// ACQUIRE load on exit. 1 memset + 1 kernel dispatch.
// ---------------------------------------------------------------------------

#define DIMN 64
#define BATCH 1024
#define HIDF 2048   // DIM*HID
#define SPLITK 4
#define NT2 32      // out2 partial count (= HIDF/64 n-tiles)
#define NB 512      // persistent blocks (2 per CU)
#define NGRP 16     // barrier groups (32 blocks each)

typedef __attribute__((ext_vector_type(8))) short short8;
typedef __attribute__((ext_vector_type(4))) float floatx4;
typedef __hip_bfloat16 bf16;

__device__ __forceinline__ float softplusf_(float t) {
    return fmaxf(t, 0.f) + log1pf(__expf(-fabsf(t)));
}

__device__ __forceinline__ float bf2f(short v) {
    union { unsigned u; float f; } x;
    x.u = ((unsigned)(unsigned short)v) << 16;
    return x.f;
}

__device__ __forceinline__ void gl_lds16(const void* g, void* l) {
    __builtin_amdgcn_global_load_lds(
        (const __attribute__((address_space(1))) unsigned int*)g,
        (__attribute__((address_space(3))) unsigned int*)l, 16, 0, 0);
}

__device__ __forceinline__ void tanh_sech2_(float p, float& th, float& s2) {
    float t = __expf(-2.f * fabsf(p));
    float opt = 1.f + t;
    float inv = 1.f / opt;
    th = copysignf((1.f - t) * inv, p);
    s2 = 4.f * t * inv * inv;
}

// ---------------------------------------------------------------------------
// Grid barrier, hierarchical wake.
// bar layout (ints, stride 32 = 128B lines):
//   [g*32]            g in [0,16)  : per-group arrival counters
//   [NGRP*32]                      : root counter
//   [(NGRP+1+g)*32]   g in [0,16)  : per-group generation flags
// Release chain: arriver acq_rel(gcnt) -> last acq_rel(root) -> root-finisher
// release-add each flag; waiter relaxed-polls own flag, ACQUIRE load on exit.
// ---------------------------------------------------------------------------
__device__ __forceinline__ void gridbar(int* bar, int bid)
{
    __syncthreads();
    if (threadIdx.x == 0) {
        int grp = bid & (NGRP - 1);
        int* gcnt  = bar + grp * 32;
        int* root  = bar + NGRP * 32;
        int* gflag = bar + (NGRP + 1 + grp) * 32;
        int g = __hip_atomic_load(gflag, __ATOMIC_RELAXED, __HIP_MEMORY_SCOPE_AGENT);
        int a = __hip_atomic_fetch_add(gcnt, 1, __ATOMIC_ACQ_REL, __HIP_MEMORY_SCOPE_AGENT) + 1;
        if (a == NB / NGRP) {
            __hip_atomic_store(gcnt, 0, __ATOMIC_RELAXED, __HIP_MEMORY_SCOPE_AGENT);
            int r = __hip_atomic_fetch_add(root, 1, __ATOMIC_ACQ_REL, __HIP_MEMORY_SCOPE_AGENT) + 1;
            if (r == NGRP) {
                __hip_atomic_store(root, 0, __ATOMIC_RELAXED, __HIP_MEMORY_SCOPE_AGENT);
#pragma unroll
                for (int i = 0; i < NGRP; ++i)
                    __hip_atomic_fetch_add(bar + (NGRP + 1 + i) * 32, 1,
                                           __ATOMIC_RELEASE, __HIP_MEMORY_SCOPE_AGENT);
            } else {
                while (__hip_atomic_load(gflag, __ATOMIC_RELAXED, __HIP_MEMORY_SCOPE_AGENT) == g)
                    __builtin_amdgcn_s_sleep(8);
            }
        } else {
            while (__hip_atomic_load(gflag, __ATOMIC_RELAXED, __HIP_MEMORY_SCOPE_AGENT) == g)
                __builtin_amdgcn_s_sleep(8);
        }
        (void)__hip_atomic_load(gflag, __ATOMIC_ACQUIRE, __HIP_MEMORY_SCOPE_AGENT);
    }
    __syncthreads();
}

// ---------------------------------------------------------------------------
// prep row worker (R16 form): one wave per output row r of W (out_f x INF).
// ---------------------------------------------------------------------------
template<int INF>
__device__ __forceinline__ void prep_row(
    const float* __restrict__ W, const float* __restrict__ dw,
    void* __restrict__ wn_out, float* __restrict__ eg,
    int r, int lane, int out_f, int ob, int ib, int transpose, int bf16out)
{
    constexpr int NI = INF / 64;
    int d = r / ob;
    int c0 = d * ib;
    int c1 = c0 + ib;
    const float* Wr = W + (size_t)r * INF;

    float vv[NI];
    float ss = 0.f;
#pragma unroll
    for (int i = 0; i < NI; ++i) {
        int c = lane + i * 64;
        float wraw = Wr[c];
        float wv = (c < c0) ? wraw : ((c < c1) ? __expf(wraw) : 0.f);
        vv[i] = wv;
        ss += wv * wv;
    }
    for (int off = 32; off > 0; off >>= 1) ss += __shfl_xor(ss, off, 64);

    float dwr = dw[r];
    float scale = __expf(dwr) / sqrtf(ss);
    float logt = dwr - 0.5f * __logf(ss);

#pragma unroll
    for (int i = 0; i < NI; ++i) {
        int c = lane + i * 64;
        float val = scale * vv[i];
        if (bf16out) {
            ((bf16*)wn_out)[(size_t)r * INF + c] = __float2bfloat16(val);
        } else if (transpose) {
            ((float*)wn_out)[(size_t)c * out_f + r] = val;
        } else {
            ((float*)wn_out)[(size_t)r * INF + c] = val;
        }
    }
    if (lane < ib) eg[(size_t)r * ib + lane] = __expf(logt + Wr[c0 + lane]);
}

// ---------------------------------------------------------------------------
// gemm0 stage body. task = (bx in [0,8), by in [0,64)).
// ---------------------------------------------------------------------------
__device__ void dev_gemm0(int bx, int by,
    const float* __restrict__ xin, const float* __restrict__ wn0T,
    const float* __restrict__ bias, const float* __restrict__ eg0,
    bf16* __restrict__ h0, bf16* __restrict__ g0e, char* smem_, int tid)
{
    float (*xs)[DIMN] = (float(*)[DIMN])smem_;
    int b0 = by * 16;
    {
        const float4* src = (const float4*)(xin + (size_t)b0 * DIMN);
        ((float4*)xs)[tid] = src[tid];
    }
    __syncthreads();
    int n = bx * 256 + tid;

    float acc[16];
#pragma unroll
    for (int j = 0; j < 16; ++j) acc[j] = 0.f;

#pragma unroll 4
    for (int c4 = 0; c4 < 16; ++c4) {
        int c = c4 * 4;
        float w0 = wn0T[(size_t)(c + 0) * HIDF + n];
        float w1 = wn0T[(size_t)(c + 1) * HIDF + n];
        float w2 = wn0T[(size_t)(c + 2) * HIDF + n];
        float w3 = wn0T[(size_t)(c + 3) * HIDF + n];
#pragma unroll
        for (int j = 0; j < 16; ++j) {
            float4 x4 = *(const float4*)&xs[j][c];
            acc[j] = fmaf(x4.x, w0, acc[j]);
            acc[j] = fmaf(x4.y, w1, acc[j]);
            acc[j] = fmaf(x4.z, w2, acc[j]);
            acc[j] = fmaf(x4.w, w3, acc[j]);
        }
    }
    float bv = bias[n], egv = eg0[n];
#pragma unroll
    for (int j = 0; j < 16; ++j) {
        float p = acc[j] + bv;
        float th, s2;
        tanh_sech2_(p, th, s2);
        size_t idx = (size_t)(b0 + j) * HIDF + n;
        h0[idx] = __float2bfloat16(th);
        g0e[idx] = __float2bfloat16(egv * s2);
    }
    __syncthreads();
}

// ---------------------------------------------------------------------------
// gemm1 stage body: live triangular (jn,kz) pairs only. 40 pairs x 8 m-tiles.
// ---------------------------------------------------------------------------
__constant__ unsigned char G1_JN[40] = {
    3,4,5,6,7,7,8,8,9,9,10,10,11,11,11,12,12,12,13,13,13,14,14,14,
    15,15,15,15, 2,6,10,14, 1,5,9,13, 0,4,8,12 };
__constant__ unsigned char G1_KZ[40] = {
    0,0,0,0,0,1,0,1,0,1, 0, 1, 0, 1, 2, 0, 1, 2, 0, 1, 2, 0, 1, 2,
     0, 1, 2, 3, 0,1, 2, 3, 0,1,2,3, 0,1,2,3 };

#define G1BK 64
__device__ void dev_gemm1(int pr, int my,
    const bf16* __restrict__ A, const bf16* __restrict__ B,
    bf16* __restrict__ part, char* smem_, int tid)
{
    const int K = HIDF, N = HIDF;
    int jn = G1_JN[pr];
    int kz = G1_KZ[pr];
    int kbase = kz * (K / SPLITK);
    int kend = (jn + 1) * 128 - kbase;
    if (kend > K / SPLITK) kend = K / SPLITK;

    short* As = (short*)smem_;            // [128][64] swizzled, 16 KB
    short* Bs = (short*)(smem_ + 16384);  // [128][64] swizzled, 16 KB
    int lane = tid & 63;
    int wave = tid >> 6;
    int n0 = jn * 128;
    int m0 = my * 128;
    int wr = wave >> 1;
    int wc = wave & 1;

    int rf = lane & 15;
    int q = lane >> 4;

    const char* agp[4];
    const char* bgp[4];
    char* alds[4];
    char* blds[4];
#pragma unroll
    for (int s = 0; s < 4; ++s) {
        int c = tid + s * 256;
        int row = c >> 3;
        int kc = (c & 7) ^ (row & 7);
        agp[s] = (const char*)A + ((size_t)(m0 + row) * K + kbase) * 2 + kc * 16;
        bgp[s] = (const char*)B + ((size_t)(n0 + row) * K + kbase) * 2 + kc * 16;
        alds[s] = (char*)As + c * 16;
        blds[s] = (char*)Bs + c * 16;
    }

    floatx4 acc[4][4];
#pragma unroll
    for (int i = 0; i < 4; ++i)
#pragma unroll
        for (int j = 0; j < 4; ++j) acc[i][j] = (floatx4){0.f, 0.f, 0.f, 0.f};

    int rowA0 = wr * 64 + rf;
    int rowB0 = wc * 64 + rf;

    for (int k0 = 0; k0 < kend; k0 += G1BK) {
        size_t kb = (size_t)k0 * 2;
        __syncthreads();
#pragma unroll
        for (int s = 0; s < 4; ++s) {
            gl_lds16(agp[s] + kb, alds[s]);
            gl_lds16(bgp[s] + kb, blds[s]);
        }
        __syncthreads();

#pragma unroll
        for (int s = 0; s < 2; ++s) {
            short8 af[4], bfv[4];
#pragma unroll
            for (int i = 0; i < 4; ++i) {
                int row = rowA0 + i * 16;
                af[i] = *(const short8*)&As[row * 64 + (((s * 4 + q) ^ (row & 7)) * 8)];
            }
#pragma unroll
            for (int j = 0; j < 4; ++j) {
                int row = rowB0 + j * 16;
                bfv[j] = *(const short8*)&Bs[row * 64 + (((s * 4 + q) ^ (row & 7)) * 8)];
            }
#pragma unroll
            for (int i = 0; i < 4; ++i)
#pragma unroll
                for (int j = 0; j < 4; ++j)
                    acc[i][j] = __builtin_amdgcn_mfma_f32_16x16x32_bf16(af[i], bfv[j], acc[i][j], 0, 0, 0);
        }
    }

    bf16* pk = part + (size_t)kz * BATCH * HIDF;
    int col = lane & 15;
    int rq = (lane >> 4) * 4;
#pragma unroll
    for (int i = 0; i < 4; ++i) {
#pragma unroll
        for (int j = 0; j < 4; ++j) {
            int n = n0 + wc * 64 + j * 16 + col;
#pragma unroll
            for (int r = 0; r < 4; ++r) {
                int m = m0 + wr * 64 + i * 16 + rq + r;
                pk[(size_t)m * N + n] = __float2bfloat16(acc[i][j][r]);
            }
        }
    }
    __syncthreads();
}

// ---------------------------------------------------------------------------
// act_grad stage body (R19 branch-free form). task = (bx in [0,32), by in [0,16)).
// ---------------------------------------------------------------------------
__device__ void dev_actgrad(int bx, int by,
    const bf16* __restrict__ part, const float* __restrict__ bias,
    const float* __restrict__ e1, const bf16* __restrict__ g0e,
    const bf16* __restrict__ wn2b,
    bf16* __restrict__ grad1e, float* __restrict__ out2p, char* smem_, int tid)
{
    float* g0s = (float*)smem_;                       // 64 x 68 floats
    short* h1s = (short*)(smem_ + 17408);             // 64 x 68 shorts
    short* Bs2 = (short*)(smem_ + 17408 + 8704);      // 64 x 64 swizzled

    int lane = tid & 63;
    int wave = tid >> 6;
    int n0 = bx * 64;
    int b0 = by * 64;
    int np = (bx >> 3) + 1;

    {
        int c0c = tid, c1c = tid + 256;
        int r0 = c0c >> 3, k0c = (c0c & 7) ^ (r0 & 7);
        int r1 = c1c >> 3, k1c = (c1c & 7) ^ (r1 & 7);
        gl_lds16((const char*)wn2b + ((size_t)r0 * HIDF + n0) * 2 + k0c * 16,
                 (char*)Bs2 + c0c * 16);
        gl_lds16((const char*)wn2b + ((size_t)r1 * HIDF + n0) * 2 + k1c * 16,
                 (char*)Bs2 + c1c * 16);
    }

    for (int s = tid; s < 512; s += 256) {
        int row = s >> 3, c8 = s & 7;
        short8 v = *(const short8*)((const short*)g0e +
                                    (size_t)(b0 + row) * HIDF + n0 + c8 * 8);
        float4 lo = { bf2f(v[0]), bf2f(v[1]), bf2f(v[2]), bf2f(v[3]) };
        float4 hi = { bf2f(v[4]), bf2f(v[5]), bf2f(v[6]), bf2f(v[7]) };
        *(float4*)&g0s[row * 68 + c8 * 8] = lo;
        *(float4*)&g0s[row * 68 + c8 * 8 + 4] = hi;
    }

    int g = tid >> 6;
    int nl = tid & 63;
    int n = n0 + nl;

    float4 er[8];
    const float4* e1r = (const float4*)(e1 + (size_t)n * 32);
#pragma unroll
    for (int qq = 0; qq < 8; ++qq) er[qq] = e1r[qq];

    float bv = bias[n];
    int kb2 = nl & 32;
    const bf16* pp0 = part;
    const bf16* pp1 = (np > 1) ? part + (size_t)1 * BATCH * HIDF : part;
    const bf16* pp2 = (np > 2) ? part + (size_t)2 * BATCH * HIDF : part;
    const bf16* pp3 = (np > 3) ? part + (size_t)3 * BATCH * HIDF : part;
    float m1 = (np > 1) ? 1.f : 0.f;
    float m2 = (np > 2) ? 1.f : 0.f;
    float m3 = (np > 3) ? 1.f : 0.f;

    __syncthreads();

#pragma unroll
    for (int t = 0; t < 16; ++t) {
        int bl = g * 16 + t;
        int b = b0 + bl;
        size_t idx = (size_t)b * HIDF + n;
        float l0 = __bfloat162float(pp0[idx]);
        float l1 = __bfloat162float(pp1[idx]);
        float l2 = __bfloat162float(pp2[idx]);
        float l3 = __bfloat162float(pp3[idx]);
        float pre = bv + l0;
        pre = fmaf(m1, l1, pre);
        pre = fmaf(m2, l2, pre);
        pre = fmaf(m3, l3, pre);
        float th, s2;
        tanh_sech2_(pre, th, s2);
        const float* g0row = &g0s[bl * 68 + kb2];
        float dot = 0.f;
#pragma unroll
        for (int qq = 0; qq < 8; ++qq) {
            float4 gv = *(const float4*)&g0row[qq * 4];
            dot = fmaf(gv.x, er[qq].x, dot);
            dot = fmaf(gv.y, er[qq].y, dot);
            dot = fmaf(gv.z, er[qq].z, dot);
            dot = fmaf(gv.w, er[qq].w, dot);
        }
        bf16 thb = __float2bfloat16(th);
        h1s[bl * 68 + nl] = *(const short*)&thb;
        grad1e[idx] = __float2bfloat16(dot * s2);
    }
    __syncthreads();

    int rf = lane & 15;
    int q = lane >> 4;
    floatx4 acc2[4];
#pragma unroll
    for (int j = 0; j < 4; ++j) acc2[j] = (floatx4){0.f, 0.f, 0.f, 0.f};

#pragma unroll
    for (int s = 0; s < 2; ++s) {
        int rowa = wave * 16 + rf;
        short8 af = *(const short8*)&h1s[rowa * 68 + s * 32 + q * 8];
#pragma unroll
        for (int j = 0; j < 4; ++j) {
            int rowb = j * 16 + rf;
            int cp = (s * 4 + q) ^ (rowb & 7);
            short8 bfv = *(const short8*)&Bs2[rowb * 64 + cp * 8];
            acc2[j] = __builtin_amdgcn_mfma_f32_16x16x32_bf16(af, bfv, acc2[j], 0, 0, 0);
        }
    }

    float* outk = out2p + (size_t)bx * BATCH * DIMN;
    int col = lane & 15;
    int rq = (lane >> 4) * 4;
#pragma unroll
    for (int j = 0; j < 4; ++j) {
#pragma unroll
        for (int r = 0; r < 4; ++r) {
            int m = b0 + wave * 16 + rq + r;
            outk[(size_t)m * DIMN + j * 16 + col] = acc2[j][r];
        }
    }
    __syncthreads();
}

// ---------------------------------------------------------------------------
// tail stage bodies. task t in [0,256): 4 batch rows per block.
// ---------------------------------------------------------------------------
__device__ void dev_tail_trans(int t,
    const float* __restrict__ out2p, const float* __restrict__ b2,
    const float* __restrict__ e2, const bf16* __restrict__ grad1e,
    const float* __restrict__ x_cur, const float* __restrict__ gate,
    float* __restrict__ x_next, float* __restrict__ ldj, int accum_ldj, int tid)
{
    int b = t * 4 + (tid >> 6);
    int n = tid & 63;

    float o = b2[n];
#pragma unroll
    for (int p = 0; p < NT2; ++p)
        o += out2p[(size_t)p * BATCH * DIMN + (size_t)b * DIMN + n];

    float gt = gate[0];
    float sg = 1.f / (1.f + __expf(-gt));
    float xo = sg * o + (1.f - sg) * x_cur[(size_t)b * DIMN + n];
    x_next[(size_t)b * DIMN + (63 - n)] = xo;

    const short8* gr = (const short8*)((const short*)grad1e + (size_t)b * HIDF + n * 32);
    const float4* gc = (const float4*)(e2 + n * 32);
    float s = 0.f;
#pragma unroll
    for (int q = 0; q < 4; ++q) {
        short8 a8 = gr[q];
        float4 c0 = gc[2 * q], c1 = gc[2 * q + 1];
        s = fmaf(bf2f(a8[0]), c0.x, s);
        s = fmaf(bf2f(a8[1]), c0.y, s);
        s = fmaf(bf2f(a8[2]), c0.z, s);
        s = fmaf(bf2f(a8[3]), c0.w, s);
        s = fmaf(bf2f(a8[4]), c1.x, s);
        s = fmaf(bf2f(a8[5]), c1.y, s);
        s = fmaf(bf2f(a8[6]), c1.z, s);
        s = fmaf(bf2f(a8[7]), c1.w, s);
    }
    float gF = __logf(fmaxf(s, 1e-45f));
    float contrib = softplusf_(gF + gt) - softplusf_(gt);
    for (int off = 32; off > 0; off >>= 1) contrib += __shfl_xor(contrib, off, 64);
    if (n == 0) ldj[b] = accum_ldj ? (ldj[b] + contrib) : contrib;
}

__device__ void dev_tail_final(int t,
    const float* __restrict__ out2p, const float* __restrict__ b2,
    const float* __restrict__ e2, const bf16* __restrict__ grad1e,
    const float* __restrict__ ldj, float* __restrict__ out, int tid)
{
    int b = t * 4 + (tid >> 6);
    int n = tid & 63;

    float o = b2[n];
#pragma unroll
    for (int p = 0; p < NT2; ++p)
        o += out2p[(size_t)p * BATCH * DIMN + (size_t)b * DIMN + n];

    const short8* gr = (const short8*)((const short*)grad1e + (size_t)b * HIDF + n * 32);
    const float4* gc = (const float4*)(e2 + n * 32);
    float s = 0.f;
#pragma unroll
    for (int q = 0; q < 4; ++q) {
        short8 a8 = gr[q];
        float4 c0 = gc[2 * q], c1 = gc[2 * q + 1];
        s = fmaf(bf2f(a8[0]), c0.x, s);
        s = fmaf(bf2f(a8[1]), c0.y, s);
        s = fmaf(bf2f(a8[2]), c0.z, s);
        s = fmaf(bf2f(a8[3]), c0.w, s);
        s = fmaf(bf2f(a8[4]), c1.x, s);
        s = fmaf(bf2f(a8[5]), c1.y, s);
        s = fmaf(bf2f(a8[6]), c1.z, s);
        s = fmaf(bf2f(a8[7]), c1.w, s);
    }
    float gF = __logf(fmaxf(s, 1e-45f));

    float contrib = gF - 0.5f * o * o - 0.91893853320467274f;
    for (int off = 32; off > 0; off >>= 1) contrib += __shfl_xor(contrib, off, 64);
    if (n == 0) out[b] = ldj[b] + contrib;
}

// ---------------------------------------------------------------------------
// The mega-kernel.
// ---------------------------------------------------------------------------
struct MegaArgs {
    const float* x;
    const float* gate0;
    const float* gate1;
    const float* Wp[27];
    float* wn0T; float* eg0;
    bf16* wn1; float* e1;
    bf16* wn2b; float* e2;
    bf16* h0; bf16* part; bf16* g0e; bf16* grad1e;
    float* out2p; float* x1; float* x2; float* ldj;
    float* outp;
    int* bar;
};

__global__ __launch_bounds__(256, 2) void mega(MegaArgs A)
{
    __shared__ __align__(16) char smem[34304];
    const int bid = blockIdx.x;
    const int tid = threadIdx.x;
    const int wave = tid >> 6, lane = tid & 63;

    // ---- stage 0: prep (all 3 flows) : 3120 block-tasks x 4 waves ----
    for (int tb = bid; tb < 3120; tb += NB) {
        int blk = tb * 4 + wave;
        int f = blk / 4160;
        int rem = blk - f * 4160;
        float* wn0T = A.wn0T + (size_t)f * DIMN * HIDF;
        float* eg0  = A.eg0  + (size_t)f * HIDF;
        bf16* wn1   = A.wn1  + (size_t)f * HIDF * HIDF;
        float* e1   = A.e1   + (size_t)f * HIDF * 32;
        bf16* wn2b  = A.wn2b + (size_t)f * DIMN * HIDF;
        float* e2   = A.e2   + (size_t)f * DIMN * 32;
        if (rem < HIDF) {
            prep_row<DIMN>(A.Wp[f*9+0], A.Wp[f*9+1], wn0T, eg0, rem, lane, HIDF, 32, 1, 1, 0);
        } else if (rem < 2 * HIDF) {
            prep_row<HIDF>(A.Wp[f*9+3], A.Wp[f*9+4], wn1, e1, rem - HIDF, lane, HIDF, 32, 32, 0, 1);
        } else {
            prep_row<HIDF>(A.Wp[f*9+6], A.Wp[f*9+7], wn2b, e2, rem - 2*HIDF, lane, DIMN, 1, 32, 0, 1);
        }
    }
    gridbar(A.bar, bid);

    // ---- gemm0 flow 0 ----
    if (bid < 512)
        dev_gemm0(bid & 7, bid >> 3, A.x, A.wn0T, A.Wp[2], A.eg0, A.h0, A.g0e, smem, tid);
    gridbar(A.bar, bid);

    const float* xcur = A.x;
#pragma unroll 1
    for (int f = 0; f < 3; ++f) {
        const bf16* wn1f  = A.wn1  + (size_t)f * HIDF * HIDF;
        const float* e1f  = A.e1   + (size_t)f * HIDF * 32;
        const bf16* wn2bf = A.wn2b + (size_t)f * DIMN * HIDF;
        const float* e2f  = A.e2   + (size_t)f * DIMN * 32;

        // gemm1: 320 tasks
        if (bid < 320)
            dev_gemm1(bid >> 3, bid & 7, A.h0, wn1f, A.part, smem, tid);
        gridbar(A.bar, bid);

        // act_grad: 512 tasks
        dev_actgrad(bid & 31, bid >> 5, A.part, A.Wp[f*9+5], e1f, A.g0e,
                    wn2bf, A.grad1e, A.out2p, smem, tid);
        gridbar(A.bar, bid);

        if (f < 2) {
            const float* gate = (f == 0) ? A.gate0 : A.gate1;
            float* xnext = (f == 0) ? A.x1 : A.x2;
            if (bid < 256)
                dev_tail_trans(bid, A.out2p, A.Wp[f*9+8], e2f, A.grad1e,
                               xcur, gate, xnext, A.ldj, f, tid);
            gridbar(A.bar, bid);

            dev_gemm0(bid & 7, bid >> 3, xnext,
                      A.wn0T + (size_t)(f+1) * DIMN * HIDF, A.Wp[(f+1)*9+2],
                      A.eg0 + (size_t)(f+1) * HIDF, A.h0, A.g0e, smem, tid);
            gridbar(A.bar, bid);
            xcur = xnext;
        } else {
            if (bid < 256)
                dev_tail_final(bid, A.out2p, A.Wp[f*9+8], e2f, A.grad1e,
                               A.ldj, A.outp, tid);
        }
    }
}

// ---------------------------------------------------------------------------
extern "C" void kernel_launch(void* const* d_in, const int* in_sizes, int n_in,
                              void* d_out, int out_size, void* d_ws, size_t ws_size,
                              hipStream_t stream)
{
    (void)in_sizes; (void)n_in; (void)out_size; (void)ws_size;

    char* ws = (char*)d_ws;
    size_t ofs = 0;
    auto alloc = [&](size_t bytes) { char* p = ws + ofs; ofs += (bytes + 255) & ~(size_t)255; return p; };

    MegaArgs A;
    A.x = (const float*)d_in[0];
    A.gate0 = (const float*)d_in[28];
    A.gate1 = (const float*)d_in[29];
    for (int f = 0; f < 3; ++f)
        for (int i = 0; i < 9; ++i)
            A.Wp[f * 9 + i] = (const float*)d_in[1 + f * 9 + i];

    A.wn1    = (bf16*)alloc((size_t)3 * HIDF * HIDF * 2);   // 24 MB
    A.wn2b   = (bf16*)alloc((size_t)3 * DIMN * HIDF * 2);
    A.wn0T   = (float*)alloc((size_t)3 * DIMN * HIDF * 4);
    A.eg0    = (float*)alloc((size_t)3 * HIDF * 4);
    A.e1     = (float*)alloc((size_t)3 * HIDF * 32 * 4);
    A.e2     = (float*)alloc((size_t)3 * DIMN * 32 * 4);
    A.h0     = (bf16*)alloc((size_t)BATCH * HIDF * 2);
    A.part   = (bf16*)alloc((size_t)SPLITK * BATCH * HIDF * 2); // 16 MB
    A.g0e    = (bf16*)alloc((size_t)BATCH * HIDF * 2);
    A.grad1e = (bf16*)alloc((size_t)BATCH * HIDF * 2);
    A.out2p  = (float*)alloc((size_t)NT2 * BATCH * DIMN * 4);   // 8 MB
    A.x1     = (float*)alloc((size_t)BATCH * DIMN * 4);
    A.x2     = (float*)alloc((size_t)BATCH * DIMN * 4);
    A.ldj    = (float*)alloc(BATCH * 4);
    A.bar    = (int*)alloc((2 * NGRP + 2) * 32 * sizeof(int));
    A.outp   = (float*)d_out;

    hipMemsetAsync(A.bar, 0, (2 * NGRP + 2) * 32 * sizeof(int), stream);
    mega<<<dim3(NB), dim3(256), 0, stream>>>(A);
}

// Round 7
// 307.968 us; speedup vs baseline: 3.9462x; 2.1562x over previous
//
#include <hip/hip_runtime.h>
#include <hip/hip_bf16.h>
#include <math.h>

// ---------------------------------------------------------------------------
// BNAF flow (DIM=64, HID=32, B=1024).  R22: revert mega (R20/R21: grid-sync
// forces per-XCD L2 flush, 2x slower than dispatch boundaries). Base = R19
// (291us) with: (a) tail_trans(f)+gemm0(f+1) fused block-locally (reversal
// is within-row -> block owning rows 4b..4b+3 feeds its own gemm0 phase);
// (b) gemm1 double-buffered staging (issue next K-tile before computing
// current; 1 barrier/iter). 11 dispatches.
// ---------------------------------------------------------------------------

#define DIMN 64
#define BATCH 1024
#define HIDF 2048   // DIM*HID
#define SPLITK 4
#define NT2 32      // out2 partial count (= HIDF/64 n-tiles)

typedef __attribute__((ext_vector_type(8))) short short8;
typedef __attribute__((ext_vector_type(4))) float floatx4;
typedef __hip_bfloat16 bf16;

__device__ __forceinline__ float softplusf_(float t) {
    return fmaxf(t, 0.f) + log1pf(__expf(-fabsf(t)));
}

__device__ __forceinline__ float bf2f(short v) {
    union { unsigned u; float f; } x;
    x.u = ((unsigned)(unsigned short)v) << 16;
    return x.f;
}

__device__ __forceinline__ void gl_lds16(const void* g, void* l) {
    __builtin_amdgcn_global_load_lds(
        (const __attribute__((address_space(1))) unsigned int*)g,
        (__attribute__((address_space(3))) unsigned int*)l, 16, 0, 0);
}

// tanh + sech^2 from ONE exp.
__device__ __forceinline__ void tanh_sech2_(float p, float& th, float& s2) {
    float t = __expf(-2.f * fabsf(p));
    float opt = 1.f + t;
    float inv = 1.f / opt;
    th = copysignf((1.f - t) * inv, p);
    s2 = 4.f * t * inv * inv;
}

// ---------------------------------------------------------------------------
// prep row worker (R16 form): one wave per output row r of W (out_f x INF).
// ---------------------------------------------------------------------------
template<int INF>
__device__ __forceinline__ void prep_row(
    const float* __restrict__ W, const float* __restrict__ dw,
    void* __restrict__ wn_out, float* __restrict__ eg,
    int r, int lane, int out_f, int ob, int ib, int transpose, int bf16out)
{
    constexpr int NI = INF / 64;
    int d = r / ob;
    int c0 = d * ib;
    int c1 = c0 + ib;
    const float* Wr = W + (size_t)r * INF;

    float vv[NI];
    float ss = 0.f;
#pragma unroll
    for (int i = 0; i < NI; ++i) {
        int c = lane + i * 64;
        float wraw = Wr[c];
        float wv = (c < c0) ? wraw : ((c < c1) ? __expf(wraw) : 0.f);
        vv[i] = wv;
        ss += wv * wv;
    }
    for (int off = 32; off > 0; off >>= 1) ss += __shfl_xor(ss, off, 64);

    float dwr = dw[r];
    float scale = __expf(dwr) / sqrtf(ss);
    float logt = dwr - 0.5f * __logf(ss);

#pragma unroll
    for (int i = 0; i < NI; ++i) {
        int c = lane + i * 64;
        float val = scale * vv[i];
        if (bf16out) {
            ((bf16*)wn_out)[(size_t)r * INF + c] = __float2bfloat16(val);
        } else if (transpose) {
            ((float*)wn_out)[(size_t)c * out_f + r] = val;
        } else {
            ((float*)wn_out)[(size_t)r * INF + c] = val;
        }
    }
    if (lane < ib) eg[(size_t)r * ib + lane] = __expf(logt + Wr[c0 + lane]);
}

struct PrepIn { const float *W0, *dw0, *W1, *dw1, *W2, *dw2; };

// all three flows' preps in ONE launch: grid 3 * (2048+2048+64) = 12480
__global__ __launch_bounds__(64) void prep_mega(
    PrepIn p0, PrepIn p1, PrepIn p2,
    float* __restrict__ wn0T_all, float* __restrict__ eg0_all,
    bf16* __restrict__ wn1_all, float* __restrict__ e1_all,
    bf16* __restrict__ wn2b_all, float* __restrict__ e2_all)
{
    int blk = blockIdx.x;
    int lane = threadIdx.x;
    int f = blk / 4160;
    int rem = blk - f * 4160;
    PrepIn P = (f == 0) ? p0 : ((f == 1) ? p1 : p2);

    float* wn0T = wn0T_all + (size_t)f * DIMN * HIDF;
    float* eg0  = eg0_all  + (size_t)f * HIDF;
    bf16* wn1   = wn1_all + (size_t)f * HIDF * HIDF;
    float* e1   = e1_all   + (size_t)f * HIDF * 32;
    bf16* wn2b  = wn2b_all + (size_t)f * DIMN * HIDF;
    float* e2   = e2_all   + (size_t)f * DIMN * 32;

    if (rem < HIDF) {
        prep_row<DIMN>(P.W0, P.dw0, wn0T, eg0, rem, lane, HIDF, 32, 1, 1, 0);
    } else if (rem < 2 * HIDF) {
        prep_row<HIDF>(P.W1, P.dw1, wn1, e1, rem - HIDF, lane, HIDF, 32, 32, 0, 1);
    } else {
        prep_row<HIDF>(P.W2, P.dw2, wn2b, e2, rem - 2 * HIDF, lane, DIMN, 1, 32, 0, 1);
    }
}

// ---------------------------------------------------------------------------
// gemm0_act (flow 0 only): pre0 = x @ wn0T + b0 ; h0 = tanh bf16;
// g0e = eg0 * sech^2 (bf16). grid (8, 64), 256 threads.
// ---------------------------------------------------------------------------
__global__ __launch_bounds__(256) void gemm0_act(
    const float* __restrict__ xin, const float* __restrict__ wn0T,
    const float* __restrict__ bias, const float* __restrict__ eg0,
    bf16* __restrict__ h0, bf16* __restrict__ g0e)
{
    __shared__ float xs[16][DIMN];
    int b0 = blockIdx.y * 16;
    {
        const float4* src = (const float4*)(xin + (size_t)b0 * DIMN);
        ((float4*)xs)[threadIdx.x] = src[threadIdx.x];
    }
    __syncthreads();
    int n = blockIdx.x * 256 + threadIdx.x;

    float acc[16];
#pragma unroll
    for (int j = 0; j < 16; ++j) acc[j] = 0.f;

#pragma unroll 4
    for (int c4 = 0; c4 < 16; ++c4) {
        int c = c4 * 4;
        float w0 = wn0T[(size_t)(c + 0) * HIDF + n];
        float w1 = wn0T[(size_t)(c + 1) * HIDF + n];
        float w2 = wn0T[(size_t)(c + 2) * HIDF + n];
        float w3 = wn0T[(size_t)(c + 3) * HIDF + n];
#pragma unroll
        for (int j = 0; j < 16; ++j) {
            float4 x4 = *(const float4*)&xs[j][c];
            acc[j] = fmaf(x4.x, w0, acc[j]);
            acc[j] = fmaf(x4.y, w1, acc[j]);
            acc[j] = fmaf(x4.z, w2, acc[j]);
            acc[j] = fmaf(x4.w, w3, acc[j]);
        }
    }
    float bv = bias[n], egv = eg0[n];
#pragma unroll
    for (int j = 0; j < 16; ++j) {
        float p = acc[j] + bv;
        float th, s2;
        tanh_sech2_(p, th, s2);
        size_t idx = (size_t)(b0 + j) * HIDF + n;
        h0[idx] = __float2bfloat16(th);
        g0e[idx] = __float2bfloat16(egv * s2);
    }
}

// ---------------------------------------------------------------------------
// gemm1_part: 128x128 tile, 4x4 frags/wave, BK=64, XOR swizzle, LPT-sorted
// live triangular schedule (40 pairs x 8 m-tiles = 320 blocks). R22: 2-phase
// double-buffered staging: issue next K-tile's global_load_lds BEFORE
// computing current; single barrier per iter (vmcnt drains at barrier after
// compute -> load latency hidden under MFMAs). LDS 64KB -> 2 blocks/CU.
// ---------------------------------------------------------------------------
__constant__ unsigned char G1_JN[40] = {
    3,4,5,6,7,7,8,8,9,9,10,10,11,11,11,12,12,12,13,13,13,14,14,14,
    15,15,15,15, 2,6,10,14, 1,5,9,13, 0,4,8,12 };
__constant__ unsigned char G1_KZ[40] = {
    0,0,0,0,0,1,0,1,0,1, 0, 1, 0, 1, 2, 0, 1, 2, 0, 1, 2, 0, 1, 2,
     0, 1, 2, 3, 0,1, 2, 3, 0,1,2,3, 0,1,2,3 };

#define G1BK 64
__global__ __launch_bounds__(256) void gemm1_part(
    const bf16* __restrict__ A, const bf16* __restrict__ B,
    bf16* __restrict__ part)
{
    __shared__ __align__(16) char smem_[65536];   // 2 bufs x (A 16KB + B 16KB)
    const int K = HIDF, N = HIDF;
    int pr = blockIdx.x >> 3;
    int my = blockIdx.x & 7;
    int jn = G1_JN[pr];
    int kz = G1_KZ[pr];
    int kbase = kz * (K / SPLITK);
    int kend = (jn + 1) * 128 - kbase;
    if (kend > K / SPLITK) kend = K / SPLITK;

    int tid = threadIdx.x;
    int lane = tid & 63;
    int wave = tid >> 6;
    int n0 = jn * 128;
    int m0 = my * 128;
    int wr = wave >> 1;
    int wc = wave & 1;
    int rf = lane & 15;
    int q = lane >> 4;

    const char* agp[4];
    const char* bgp[4];
    int lofs[4];
#pragma unroll
    for (int s = 0; s < 4; ++s) {
        int c = tid + s * 256;
        int row = c >> 3;
        int kc = (c & 7) ^ (row & 7);
        agp[s] = (const char*)A + ((size_t)(m0 + row) * K + kbase) * 2 + kc * 16;
        bgp[s] = (const char*)B + ((size_t)(n0 + row) * K + kbase) * 2 + kc * 16;
        lofs[s] = c * 16;
    }

    floatx4 acc[4][4];
#pragma unroll
    for (int i = 0; i < 4; ++i)
#pragma unroll
        for (int j = 0; j < 4; ++j) acc[i][j] = (floatx4){0.f, 0.f, 0.f, 0.f};

    int rowA0 = wr * 64 + rf;
    int rowB0 = wc * 64 + rf;

    // prologue: stage k=0 into buf 0
    {
        char* base = smem_;
#pragma unroll
        for (int s = 0; s < 4; ++s) {
            gl_lds16(agp[s], base + lofs[s]);
            gl_lds16(bgp[s], base + 16384 + lofs[s]);
        }
    }
    __syncthreads();   // compiler drains vmcnt(0) -> buf0 ready

    int cur = 0;
    for (int k0 = 0; k0 < kend; k0 += G1BK) {
        int nk = k0 + G1BK;
        if (nk < kend) {               // issue NEXT tile before computing
            size_t kb = (size_t)nk * 2;
            char* base = smem_ + (cur ^ 1) * 32768;
#pragma unroll
            for (int s = 0; s < 4; ++s) {
                gl_lds16(agp[s] + kb, base + lofs[s]);
                gl_lds16(bgp[s] + kb, base + 16384 + lofs[s]);
            }
        }

        const short* As = (const short*)(smem_ + cur * 32768);
        const short* Bs = (const short*)(smem_ + cur * 32768 + 16384);
#pragma unroll
        for (int s = 0; s < 2; ++s) {
            short8 af[4], bfv[4];
#pragma unroll
            for (int i = 0; i < 4; ++i) {
                int row = rowA0 + i * 16;
                af[i] = *(const short8*)&As[row * 64 + (((s * 4 + q) ^ (row & 7)) * 8)];
            }
#pragma unroll
            for (int j = 0; j < 4; ++j) {
                int row = rowB0 + j * 16;
                bfv[j] = *(const short8*)&Bs[row * 64 + (((s * 4 + q) ^ (row & 7)) * 8)];
            }
#pragma unroll
            for (int i = 0; i < 4; ++i)
#pragma unroll
                for (int j = 0; j < 4; ++j)
                    acc[i][j] = __builtin_amdgcn_mfma_f32_16x16x32_bf16(af[i], bfv[j], acc[i][j], 0, 0, 0);
        }
        __syncthreads();   // drains next-buf loads (had compute-time to land)
        cur ^= 1;
    }

    bf16* pk = part + (size_t)kz * BATCH * HIDF;
    int col = lane & 15;
    int rq = (lane >> 4) * 4;
#pragma unroll
    for (int i = 0; i < 4; ++i) {
#pragma unroll
        for (int j = 0; j < 4; ++j) {
            int n = n0 + wc * 64 + j * 16 + col;
#pragma unroll
            for (int r = 0; r < 4; ++r) {
                int m = m0 + wr * 64 + i * 16 + rq + r;
                pk[(size_t)m * N + n] = __float2bfloat16(acc[i][j][r]);
            }
        }
    }
}

// ---------------------------------------------------------------------------
// act_grad_gemm2 (R19 branch-free form).
// ---------------------------------------------------------------------------
__global__ __launch_bounds__(256) void act_grad_gemm2(
    const bf16* __restrict__ part, const float* __restrict__ bias,
    const float* __restrict__ e1, const bf16* __restrict__ g0e,
    const bf16* __restrict__ wn2b,
    bf16* __restrict__ grad1e, float* __restrict__ out2p)
{
    __shared__ char smem[17408 + 8704 + 8192];
    float* g0s = (float*)smem;
    short* h1s = (short*)(smem + 17408);
    short* Bs2 = (short*)(smem + 17408 + 8704);

    int tid = threadIdx.x;
    int lane = tid & 63;
    int wave = tid >> 6;
    int bx = blockIdx.x;
    int n0 = bx * 64;
    int b0 = blockIdx.y * 64;
    int np = (bx >> 3) + 1;

    {
        int c0c = tid, c1c = tid + 256;
        int r0 = c0c >> 3, k0c = (c0c & 7) ^ (r0 & 7);
        int r1 = c1c >> 3, k1c = (c1c & 7) ^ (r1 & 7);
        gl_lds16((const char*)wn2b + ((size_t)r0 * HIDF + n0) * 2 + k0c * 16,
                 (char*)Bs2 + c0c * 16);
        gl_lds16((const char*)wn2b + ((size_t)r1 * HIDF + n0) * 2 + k1c * 16,
                 (char*)Bs2 + c1c * 16);
    }

    for (int s = tid; s < 512; s += 256) {
        int row = s >> 3, c8 = s & 7;
        short8 v = *(const short8*)((const short*)g0e +
                                    (size_t)(b0 + row) * HIDF + n0 + c8 * 8);
        float4 lo = { bf2f(v[0]), bf2f(v[1]), bf2f(v[2]), bf2f(v[3]) };
        float4 hi = { bf2f(v[4]), bf2f(v[5]), bf2f(v[6]), bf2f(v[7]) };
        *(float4*)&g0s[row * 68 + c8 * 8] = lo;
        *(float4*)&g0s[row * 68 + c8 * 8 + 4] = hi;
    }

    int g = tid >> 6;
    int nl = tid & 63;
    int n = n0 + nl;

    float4 er[8];
    const float4* e1r = (const float4*)(e1 + (size_t)n * 32);
#pragma unroll
    for (int qq = 0; qq < 8; ++qq) er[qq] = e1r[qq];

    float bv = bias[n];
    int kb2 = nl & 32;
    const bf16* pp0 = part;
    const bf16* pp1 = (np > 1) ? part + (size_t)1 * BATCH * HIDF : part;
    const bf16* pp2 = (np > 2) ? part + (size_t)2 * BATCH * HIDF : part;
    const bf16* pp3 = (np > 3) ? part + (size_t)3 * BATCH * HIDF : part;
    float m1 = (np > 1) ? 1.f : 0.f;
    float m2 = (np > 2) ? 1.f : 0.f;
    float m3 = (np > 3) ? 1.f : 0.f;

    __syncthreads();

#pragma unroll
    for (int t = 0; t < 16; ++t) {
        int bl = g * 16 + t;
        int b = b0 + bl;
        size_t idx = (size_t)b * HIDF + n;
        float l0 = __bfloat162float(pp0[idx]);
        float l1 = __bfloat162float(pp1[idx]);
        float l2 = __bfloat162float(pp2[idx]);
        float l3 = __bfloat162float(pp3[idx]);
        float pre = bv + l0;
        pre = fmaf(m1, l1, pre);
        pre = fmaf(m2, l2, pre);
        pre = fmaf(m3, l3, pre);
        float th, s2;
        tanh_sech2_(pre, th, s2);
        const float* g0row = &g0s[bl * 68 + kb2];
        float dot = 0.f;
#pragma unroll
        for (int qq = 0; qq < 8; ++qq) {
            float4 gv = *(const float4*)&g0row[qq * 4];
            dot = fmaf(gv.x, er[qq].x, dot);
            dot = fmaf(gv.y, er[qq].y, dot);
            dot = fmaf(gv.z, er[qq].z, dot);
            dot = fmaf(gv.w, er[qq].w, dot);
        }
        bf16 thb = __float2bfloat16(th);
        h1s[bl * 68 + nl] = *(const short*)&thb;
        grad1e[idx] = __float2bfloat16(dot * s2);
    }
    __syncthreads();

    int rf = lane & 15;
    int q = lane >> 4;
    floatx4 acc2[4];
#pragma unroll
    for (int j = 0; j < 4; ++j) acc2[j] = (floatx4){0.f, 0.f, 0.f, 0.f};

#pragma unroll
    for (int s = 0; s < 2; ++s) {
        int rowa = wave * 16 + rf;
        short8 af = *(const short8*)&h1s[rowa * 68 + s * 32 + q * 8];
#pragma unroll
        for (int j = 0; j < 4; ++j) {
            int rowb = j * 16 + rf;
            int cp = (s * 4 + q) ^ (rowb & 7);
            short8 bfv = *(const short8*)&Bs2[rowb * 64 + cp * 8];
            acc2[j] = __builtin_amdgcn_mfma_f32_16x16x32_bf16(af, bfv, acc2[j], 0, 0, 0);
        }
    }

    float* outk = out2p + (size_t)bx * BATCH * DIMN;
    int col = lane & 15;
    int rq = (lane >> 4) * 4;
#pragma unroll
    for (int j = 0; j < 4; ++j) {
#pragma unroll
        for (int r = 0; r < 4; ++r) {
            int m = b0 + wave * 16 + rq + r;
            outk[(size_t)m * DIMN + j * 16 + col] = acc2[j][r];
        }
    }
}

// ---------------------------------------------------------------------------
// tail_gemm0: FUSED tail_trans(f) + gemm0(f+1). Block owns 4 batch rows.
// Phase 1 (tail): o-sum over 32 out2p planes, gate-mix, ldj; x_next rows
// kept in LDS (reversal is within-row -> block-local). Phase 2 (gemm0):
// those 4 rows x all 2048 n; thread t handles n = t+256i, i<8.
// grid 256, 256 threads.
// ---------------------------------------------------------------------------
__global__ __launch_bounds__(256) void tail_gemm0(
    const float* __restrict__ out2p, const float* __restrict__ b2,
    const float* __restrict__ e2, const bf16* __restrict__ grad1e,
    const float* __restrict__ x_cur, const float* __restrict__ gate,
    float* __restrict__ x_next, float* __restrict__ ldj, int accum_ldj,
    const float* __restrict__ wn0T_n, const float* __restrict__ bias_n,
    const float* __restrict__ eg0_n,
    bf16* __restrict__ h0, bf16* __restrict__ g0e)
{
    __shared__ float xs[4][DIMN];
    int tid = threadIdx.x;
    int row = tid >> 6;
    int b = blockIdx.x * 4 + row;
    int n = tid & 63;

    // ---- phase 1: tail ----
    float o = b2[n];
#pragma unroll
    for (int p = 0; p < NT2; ++p)
        o += out2p[(size_t)p * BATCH * DIMN + (size_t)b * DIMN + n];

    float gt = gate[0];
    float sg = 1.f / (1.f + __expf(-gt));
    float xo = sg * o + (1.f - sg) * x_cur[(size_t)b * DIMN + n];
    x_next[(size_t)b * DIMN + (63 - n)] = xo;
    xs[row][63 - n] = xo;

    const short8* gr = (const short8*)((const short*)grad1e + (size_t)b * HIDF + n * 32);
    const float4* gc = (const float4*)(e2 + n * 32);
    float s = 0.f;
#pragma unroll
    for (int q = 0; q < 4; ++q) {
        short8 a8 = gr[q];
        float4 c0 = gc[2 * q], c1 = gc[2 * q + 1];
        s = fmaf(bf2f(a8[0]), c0.x, s);
        s = fmaf(bf2f(a8[1]), c0.y, s);
        s = fmaf(bf2f(a8[2]), c0.z, s);
        s = fmaf(bf2f(a8[3]), c0.w, s);
        s = fmaf(bf2f(a8[4]), c1.x, s);
        s = fmaf(bf2f(a8[5]), c1.y, s);
        s = fmaf(bf2f(a8[6]), c1.z, s);
        s = fmaf(bf2f(a8[7]), c1.w, s);
    }
    float gF = __logf(fmaxf(s, 1e-45f));
    float contrib = softplusf_(gF + gt) - softplusf_(gt);
    for (int off = 32; off > 0; off >>= 1) contrib += __shfl_xor(contrib, off, 64);
    if (n == 0) ldj[b] = accum_ldj ? (ldj[b] + contrib) : contrib;

    __syncthreads();

    // ---- phase 2: gemm0 for next flow, rows 4*blockIdx.x .. +3 ----
    int b0r = blockIdx.x * 4;
#pragma unroll 1
    for (int i = 0; i < 8; ++i) {
        int n2 = tid + (i << 8);
        float a0 = 0.f, a1 = 0.f, a2 = 0.f, a3 = 0.f;
#pragma unroll 8
        for (int c = 0; c < 64; ++c) {
            float w = wn0T_n[(size_t)c * HIDF + n2];
            a0 = fmaf(xs[0][c], w, a0);
            a1 = fmaf(xs[1][c], w, a1);
            a2 = fmaf(xs[2][c], w, a2);
            a3 = fmaf(xs[3][c], w, a3);
        }
        float bv = bias_n[n2], egv = eg0_n[n2];
        float th, s2;
        tanh_sech2_(a0 + bv, th, s2);
        h0[(size_t)(b0r + 0) * HIDF + n2] = __float2bfloat16(th);
        g0e[(size_t)(b0r + 0) * HIDF + n2] = __float2bfloat16(egv * s2);
        tanh_sech2_(a1 + bv, th, s2);
        h0[(size_t)(b0r + 1) * HIDF + n2] = __float2bfloat16(th);
        g0e[(size_t)(b0r + 1) * HIDF + n2] = __float2bfloat16(egv * s2);
        tanh_sech2_(a2 + bv, th, s2);
        h0[(size_t)(b0r + 2) * HIDF + n2] = __float2bfloat16(th);
        g0e[(size_t)(b0r + 2) * HIDF + n2] = __float2bfloat16(egv * s2);
        tanh_sech2_(a3 + bv, th, s2);
        h0[(size_t)(b0r + 3) * HIDF + n2] = __float2bfloat16(th);
        g0e[(size_t)(b0r + 3) * HIDF + n2] = __float2bfloat16(egv * s2);
    }
}

// ---------------------------------------------------------------------------
// tail_final (flow 2): out[b] = ldj[b] + sum_n(gF - 0.5*o^2 - 0.5*log(2pi))
// ---------------------------------------------------------------------------
__global__ __launch_bounds__(256) void tail_final(
    const float* __restrict__ out2p, const float* __restrict__ b2,
    const float* __restrict__ e2, const bf16* __restrict__ grad1e,
    const float* __restrict__ ldj, float* __restrict__ out)
{
    int tid = threadIdx.x;
    int b = blockIdx.x * 4 + (tid >> 6);
    int n = tid & 63;

    float o = b2[n];
#pragma unroll
    for (int p = 0; p < NT2; ++p)
        o += out2p[(size_t)p * BATCH * DIMN + (size_t)b * DIMN + n];

    const short8* gr = (const short8*)((const short*)grad1e + (size_t)b * HIDF + n * 32);
    const float4* gc = (const float4*)(e2 + n * 32);
    float s = 0.f;
#pragma unroll
    for (int q = 0; q < 4; ++q) {
        short8 a8 = gr[q];
        float4 c0 = gc[2 * q], c1 = gc[2 * q + 1];
        s = fmaf(bf2f(a8[0]), c0.x, s);
        s = fmaf(bf2f(a8[1]), c0.y, s);
        s = fmaf(bf2f(a8[2]), c0.z, s);
        s = fmaf(bf2f(a8[3]), c0.w, s);
        s = fmaf(bf2f(a8[4]), c1.x, s);
        s = fmaf(bf2f(a8[5]), c1.y, s);
        s = fmaf(bf2f(a8[6]), c1.z, s);
        s = fmaf(bf2f(a8[7]), c1.w, s);
    }
    float gF = __logf(fmaxf(s, 1e-45f));

    float contrib = gF - 0.5f * o * o - 0.91893853320467274f;
    for (int off = 32; off > 0; off >>= 1) contrib += __shfl_xor(contrib, off, 64);
    if (n == 0) out[b] = ldj[b] + contrib;
}

// ---------------------------------------------------------------------------
extern "C" void kernel_launch(void* const* d_in, const int* in_sizes, int n_in,
                              void* d_out, int out_size, void* d_ws, size_t ws_size,
                              hipStream_t stream)
{
    (void)in_sizes; (void)n_in; (void)out_size; (void)ws_size;

    const float* x = (const float*)d_in[0];
    const float* gates[2] = { (const float*)d_in[28], (const float*)d_in[29] };

    char* ws = (char*)d_ws;
    size_t ofs = 0;
    auto alloc = [&](size_t bytes) { char* p = ws + ofs; ofs += (bytes + 255) & ~(size_t)255; return p; };

    bf16* wn1_all  = (bf16*)alloc((size_t)3 * HIDF * HIDF * 2);   // 24 MB
    bf16* wn2b_all = (bf16*)alloc((size_t)3 * DIMN * HIDF * 2);
    float* wn0T_all = (float*)alloc((size_t)3 * DIMN * HIDF * 4);
    float* eg0_all  = (float*)alloc((size_t)3 * HIDF * 4);
    float* e1_all   = (float*)alloc((size_t)3 * HIDF * 32 * 4);
    float* e2_all   = (float*)alloc((size_t)3 * DIMN * 32 * 4);
    bf16* h0   = (bf16*)alloc((size_t)BATCH * HIDF * 2);
    bf16* part = (bf16*)alloc((size_t)SPLITK * BATCH * HIDF * 2); // 16 MB
    bf16* g0e    = (bf16*)alloc((size_t)BATCH * HIDF * 2);
    bf16* grad1e = (bf16*)alloc((size_t)BATCH * HIDF * 2);
    float* out2p  = (float*)alloc((size_t)NT2 * BATCH * DIMN * 4); // 8 MB
    float* x1     = (float*)alloc((size_t)BATCH * DIMN * 4);
    float* x2     = (float*)alloc((size_t)BATCH * DIMN * 4);
    float* ldj    = (float*)alloc(BATCH * 4);
    float* outp   = (float*)d_out;

    auto W = [&](int f, int i) { return (const float*)d_in[1 + f * 9 + i]; };

    PrepIn p0 = { W(0,0), W(0,1), W(0,3), W(0,4), W(0,6), W(0,7) };
    PrepIn p1 = { W(1,0), W(1,1), W(1,3), W(1,4), W(1,6), W(1,7) };
    PrepIn p2 = { W(2,0), W(2,1), W(2,3), W(2,4), W(2,6), W(2,7) };

    prep_mega<<<dim3(3 * 4160), dim3(64), 0, stream>>>(
        p0, p1, p2, wn0T_all, eg0_all, wn1_all, e1_all, wn2b_all, e2_all);

    gemm0_act<<<dim3(8, BATCH / 16), dim3(256), 0, stream>>>(
        x, wn0T_all, W(0,2), eg0_all, h0, g0e);

    const float* xcur = x;
    float* xnexts[2] = { x1, x2 };

    for (int f = 0; f < 3; ++f) {
        size_t fo1 = (size_t)f * HIDF * HIDF;
        size_t fo2 = (size_t)f * DIMN * HIDF;

        gemm1_part<<<dim3(320), dim3(256), 0, stream>>>(
            h0, wn1_all + fo1, part);

        act_grad_gemm2<<<dim3(HIDF / 64, BATCH / 64), dim3(256), 0, stream>>>(
            part, W(f,5), e1_all + (size_t)f * HIDF * 32, g0e,
            wn2b_all + fo2, grad1e, out2p);

        if (f < 2) {
            // fused tail(f) + gemm0(f+1)
            tail_gemm0<<<dim3(BATCH / 4), dim3(256), 0, stream>>>(
                out2p, W(f,8), e2_all + (size_t)f * DIMN * 32, grad1e,
                xcur, gates[f], xnexts[f], ldj, f,
                wn0T_all + (size_t)(f + 1) * DIMN * HIDF, W(f + 1, 2),
                eg0_all + (size_t)(f + 1) * HIDF, h0, g0e);
            xcur = xnexts[f];
        } else {
            tail_final<<<dim3(BATCH / 4), dim3(256), 0, stream>>>(
                out2p, W(2,8), e2_all + (size_t)2 * DIMN * 32, grad1e, ldj, outp);
        }
    }
}